// Round 6
// baseline (2502.112 us; speedup 1.0000x reference)
//
#include <hip/hip_runtime.h>

typedef int v2i __attribute__((ext_vector_type(2)));

#define QN 8192   // trajectories
#define MN 2048   // time steps
#define HN 64     // hidden units
#define LPT 32    // lanes per trajectory
#define UPL 2     // hidden units per lane

// DPP butterfly add within each 16-lane row. Full-rate VALU, no LDS.
// Identical sequence to the R2-R5 versions that passed.
template <int CTRL>
__device__ __forceinline__ float dpp_add(float v) {
    int m = __builtin_amdgcn_update_dpp(0, __float_as_int(v), CTRL, 0xf, 0xf, true);
    return v + __int_as_float(m);
}
#define DPP_QUAD_XOR1 0xB1   // quad_perm [1,0,3,2]
#define DPP_QUAD_XOR2 0x4E   // quad_perm [2,3,0,1]
#define DPP_HALF_MIRR 0x141  // row_half_mirror
#define DPP_ROW_MIRR  0x140  // row_mirror

// Sum of p[lane] + p[lane^32] in every lane, via gfx950 v_permlane32_swap_b32:
// new_vdst = {lo: p_lo, hi: p_lo_of_src} ; new_vsrc = {lo: p_hi_of_dst, hi: p_hi}
// With both inputs = p: pr.x + pr.y == p[l] + p[l^32] for all l. Pure VALU.
__device__ __forceinline__ float xor32_add(float p) {
    v2i pr = __builtin_amdgcn_permlane32_swap(__float_as_int(p), __float_as_int(p),
                                              false, false);
    return __int_as_float(pr.x) + __int_as_float(pr.y);
}

__global__ __launch_bounds__(256, 4) void rk4_nss_kernel(
    const float* __restrict__ x0p,   // (Q,2)
    const float* __restrict__ up,    // (M,Q)
    const float* __restrict__ W1,    // (3,H)
    const float* __restrict__ b1,    // (H)
    const float* __restrict__ W2,    // (H,2)
    const float* __restrict__ b2,    // (2)
    float* __restrict__ out)         // (M,Q,2)
{
    const int tid    = blockIdx.x * 256 + threadIdx.x;
    const int lane64 = threadIdx.x & 63;
    const int wid    = tid >> 6;                 // global wave id
    // Group A = rows 0,2 (lanes 0-15, 32-47); group B = rows 1,3.
    // permlane32_swap pairs rows 0<->2 and 1<->3, i.e. within-group.
    const int group  = (lane64 >> 4) & 1;
    const int traj   = 2 * wid + group;
    // Unit sub-index within the group's 32 lanes: 0..31.
    const int s      = (lane64 & 15) + ((lane64 & 32) >> 1);

    const float SC = 2.8853900817779268f;  // 2*log2(e): e^{2x} = 2^(SC*x)
    const float CL = 27.0f;  // clamp (scaled): tanh(27/SC) == 1.0f in f32;
                             // pair den-product <= 2^54, cannot overflow.

    // Lane owns hidden units j = s + k*32. W1,b1 pre-scaled by SC;
    // tanh = 1 - 2/(e^{2x}+1), "+1" folded into c0,c1, accumulate inv*(-2*W2).
    float ws10[UPL], ws11[UPL], ws12[UPL], bsb[UPL], w20n[UPL], w21n[UPL];
#pragma unroll
    for (int k = 0; k < UPL; ++k) {
        const int j = s + k * 32;
        ws10[k] = W1[j] * SC;
        ws11[k] = W1[HN + j] * SC;
        ws12[k] = W1[2 * HN + j] * SC;
        bsb[k]  = b1[j] * SC;
        w20n[k] = -2.0f * W2[2 * j];
        w21n[k] = -2.0f * W2[2 * j + 1];
    }
    float c0 = b2[0], c1 = b2[1];
    for (int j = 0; j < HN; ++j) {   // init-time only; W2 is 512 B, cache-hot
        c0 += W2[2 * j];
        c1 += W2[2 * j + 1];
    }

    float xa = x0p[2 * traj];
    float xb = x0p[2 * traj + 1];
    float ucur = up[traj];

    float2* outv = reinterpret_cast<float2*>(out);
    const bool writer = ((lane64 & 47) == 0);   // lanes 0 and 16

    float pb[UPL];  // u-dependent preactivation part, constant across 4 fevals

    auto feval = [&](float ia, float ib, float& d0, float& d1) {
        float den[UPL];
#pragma unroll
        for (int k = 0; k < UPL; ++k) {
            float pre = fmaf(ws10[k], ia, fmaf(ws11[k], ib, pb[k]));
            pre = __builtin_amdgcn_fmed3f(pre, -CL, CL);
            den[k] = __builtin_amdgcn_exp2f(pre) + 1.0f;
        }
        // Pair-batched reciprocal (R3-proven): 1 rcp for this lane's 2 dens.
        float d01 = den[0] * den[1];
        float r   = __builtin_amdgcn_rcpf(d01);
        float inv0 = r * den[1];
        float inv1 = r * den[0];

        float p0 = fmaf(inv0, w20n[0], inv1 * w20n[1]);
        float p1 = fmaf(inv0, w21n[0], inv1 * w21n[1]);

        // Reduce within each 16-lane row (4 DPP stages) ...
        p0 = dpp_add<DPP_QUAD_XOR1>(p0);  p1 = dpp_add<DPP_QUAD_XOR1>(p1);
        p0 = dpp_add<DPP_QUAD_XOR2>(p0);  p1 = dpp_add<DPP_QUAD_XOR2>(p1);
        p0 = dpp_add<DPP_HALF_MIRR>(p0);  p1 = dpp_add<DPP_HALF_MIRR>(p1);
        p0 = dpp_add<DPP_ROW_MIRR>(p0);   p1 = dpp_add<DPP_ROW_MIRR>(p1);
        // ... then across the paired row (lane ^ 32): full group of 32 lanes.
        p0 = xor32_add(p0);               p1 = xor32_add(p1);
        d0 = p0 + c0;
        d1 = p1 + c1;
    };

    for (int t = 0; t < MN; ++t) {
        // Output is the state BEFORE the update.
        if (writer) {
            outv[t * QN + traj] = make_float2(xa, xb);
        }
        // Prefetch next step's input (hidden under the 4 fevals).
        const float unext = (t + 1 < MN) ? up[(t + 1) * QN + traj] : 0.0f;

#pragma unroll
        for (int k = 0; k < UPL; ++k)
            pb[k] = fmaf(ws12[k], ucur, bsb[k]);

        float k1a, k1b, k2a, k2b, k3a, k3b, k4a, k4b;
        feval(xa, xb, k1a, k1b);
        feval(fmaf(0.5f, k1a, xa), fmaf(0.5f, k1b, xb), k2a, k2b);
        feval(fmaf(0.5f, k2a, xa), fmaf(0.5f, k2b, xb), k3a, k3b);
        feval(xa + k3a, xb + k3b, k4a, k4b);

        float ta = k2a + k3a;
        float sa = k1a + k4a;
        xa = fmaf((1.0f / 6.0f), fmaf(2.0f, ta, sa), xa);
        float tb = k2b + k3b;
        float sb = k1b + k4b;
        xb = fmaf((1.0f / 6.0f), fmaf(2.0f, tb, sb), xb);
        ucur = unext;
    }
}

extern "C" void kernel_launch(void* const* d_in, const int* in_sizes, int n_in,
                              void* d_out, int out_size, void* d_ws, size_t ws_size,
                              hipStream_t stream) {
    const float* x0 = (const float*)d_in[0];
    const float* u  = (const float*)d_in[1];
    const float* W1 = (const float*)d_in[2];
    const float* b1 = (const float*)d_in[3];
    const float* W2 = (const float*)d_in[4];
    const float* b2 = (const float*)d_in[5];
    float* out = (float*)d_out;

    // 8192 trajectories * 32 lanes = 262144 threads = 1024 blocks of 256.
    const int threads = 256;
    const int blocks  = (QN * LPT) / threads;
    rk4_nss_kernel<<<blocks, threads, 0, stream>>>(x0, u, W1, b1, W2, b2, out);
}

// Round 7
// 2052.924 us; speedup vs baseline: 1.2188x; 1.2188x over previous
//
#include <hip/hip_runtime.h>

#define QN 8192   // trajectories
#define MN 2048   // time steps
#define HN 64     // hidden units
#define LPT 8     // lanes per trajectory (8 trajectories per wave)
#define UPL 8     // hidden units per lane

// DPP butterfly add. Full-rate VALU, no LDS. Same primitives as R2-R6.
template <int CTRL>
__device__ __forceinline__ float dpp_add(float v) {
    int m = __builtin_amdgcn_update_dpp(0, __float_as_int(v), CTRL, 0xf, 0xf, true);
    return v + __int_as_float(m);
}
#define DPP_QUAD_XOR1 0xB1   // quad_perm [1,0,3,2]
#define DPP_QUAD_XOR2 0x4E   // quad_perm [2,3,0,1]
#define DPP_HALF_MIRR 0x141  // row_half_mirror: lane i <-> 7-i within each 8

__global__ __launch_bounds__(256, 1) void rk4_nss_kernel(
    const float* __restrict__ x0p,   // (Q,2)
    const float* __restrict__ up,    // (M,Q)
    const float* __restrict__ W1,    // (3,H)
    const float* __restrict__ b1,    // (H)
    const float* __restrict__ W2,    // (H,2)
    const float* __restrict__ b2,    // (2)
    float* __restrict__ out)         // (M,Q,2)
{
    const int tid  = blockIdx.x * 256 + threadIdx.x;
    const int lane = threadIdx.x & (LPT - 1);
    const int traj = tid >> 3;
    if (traj >= QN) return;

    const float SC = 2.8853900817779268f;  // 2*log2(e): e^{2x} = 2^(SC*x)
    const float CL = 27.0f;  // clamp (scaled units): tanh(27/SC=9.36)==1.0f in
                             // f32; pair den-product <= ~2^54, cannot overflow.

    // Lane owns hidden units j = lane + k*8. W1,b1 pre-scaled by SC;
    // tanh = 1 - 2/(e^{2x}+1): "+1" folded into c0,c1, accumulate inv*(-2*W2).
    float ws10[UPL], ws11[UPL], ws12[UPL], bsb[UPL], w20n[UPL], w21n[UPL];
#pragma unroll
    for (int k = 0; k < UPL; ++k) {
        const int j = lane + k * LPT;
        ws10[k] = W1[j] * SC;
        ws11[k] = W1[HN + j] * SC;
        ws12[k] = W1[2 * HN + j] * SC;
        bsb[k]  = b1[j] * SC;
        w20n[k] = -2.0f * W2[2 * j];
        w21n[k] = -2.0f * W2[2 * j + 1];
    }
    float c0 = b2[0], c1 = b2[1];
    for (int j = 0; j < HN; ++j) {   // init-time only; W2 is 512 B, cache-hot
        c0 += W2[2 * j];
        c1 += W2[2 * j + 1];
    }

    float xa = x0p[2 * traj];
    float xb = x0p[2 * traj + 1];
    float ucur = up[traj];

    float2* outv = reinterpret_cast<float2*>(out);
    const bool writer = (lane == 0);

    float pb[UPL];  // u-dependent preactivation part, constant across 4 fevals

    auto feval = [&](float ia, float ib, float& d0, float& d1) {
        float den[UPL];
#pragma unroll
        for (int k = 0; k < UPL; ++k) {
            float pre = fmaf(ws10[k], ia, fmaf(ws11[k], ib, pb[k]));
            pre = __builtin_amdgcn_fmed3f(pre, -CL, CL);
            den[k] = __builtin_amdgcn_exp2f(pre) + 1.0f;
        }
        // Pair-batched reciprocal (R3-proven): 4 independent rcp chains.
        float p0 = 0.0f, p1 = 0.0f;
#pragma unroll
        for (int k = 0; k < UPL; k += 2) {
            float d01 = den[k] * den[k + 1];
            float r   = __builtin_amdgcn_rcpf(d01);
            float inv0 = r * den[k + 1];
            float inv1 = r * den[k];
            p0 = fmaf(inv0, w20n[k], fmaf(inv1, w20n[k + 1], p0));
            p1 = fmaf(inv0, w21n[k], fmaf(inv1, w21n[k + 1], p1));
        }

        // Reduce across the 8-lane group: 3 DPP stages.
        // After xor1+xor2 each quad holds its sum; half_mirror (i<->7-i)
        // fetches the complementary quad's value.
        p0 = dpp_add<DPP_QUAD_XOR1>(p0);  p1 = dpp_add<DPP_QUAD_XOR1>(p1);
        p0 = dpp_add<DPP_QUAD_XOR2>(p0);  p1 = dpp_add<DPP_QUAD_XOR2>(p1);
        p0 = dpp_add<DPP_HALF_MIRR>(p0);  p1 = dpp_add<DPP_HALF_MIRR>(p1);
        d0 = p0 + c0;
        d1 = p1 + c1;
    };

    for (int t = 0; t < MN; ++t) {
        // Output is the state BEFORE the update.
        if (writer) {
            outv[t * QN + traj] = make_float2(xa, xb);
        }
        // Prefetch next step's input (consumed next iteration; ~full step of
        // VALU work hides the load latency even at 1 wave/SIMD).
        const float unext = (t + 1 < MN) ? up[(t + 1) * QN + traj] : 0.0f;

#pragma unroll
        for (int k = 0; k < UPL; ++k)
            pb[k] = fmaf(ws12[k], ucur, bsb[k]);

        float k1a, k1b, k2a, k2b, k3a, k3b, k4a, k4b;
        feval(xa, xb, k1a, k1b);
        feval(fmaf(0.5f, k1a, xa), fmaf(0.5f, k1b, xb), k2a, k2b);
        feval(fmaf(0.5f, k2a, xa), fmaf(0.5f, k2b, xb), k3a, k3b);
        feval(xa + k3a, xb + k3b, k4a, k4b);

        float ta = k2a + k3a;
        float sa = k1a + k4a;
        xa = fmaf((1.0f / 6.0f), fmaf(2.0f, ta, sa), xa);
        float tb = k2b + k3b;
        float sb = k1b + k4b;
        xb = fmaf((1.0f / 6.0f), fmaf(2.0f, tb, sb), xb);
        ucur = unext;
    }
}

extern "C" void kernel_launch(void* const* d_in, const int* in_sizes, int n_in,
                              void* d_out, int out_size, void* d_ws, size_t ws_size,
                              hipStream_t stream) {
    const float* x0 = (const float*)d_in[0];
    const float* u  = (const float*)d_in[1];
    const float* W1 = (const float*)d_in[2];
    const float* b1 = (const float*)d_in[3];
    const float* W2 = (const float*)d_in[4];
    const float* b2 = (const float*)d_in[5];
    float* out = (float*)d_out;

    // 8192 trajectories * 8 lanes = 65536 threads = 256 blocks of 256.
    const int threads = 256;
    const int blocks  = (QN * LPT) / threads;
    rk4_nss_kernel<<<blocks, threads, 0, stream>>>(x0, u, W1, b1, W2, b2, out);
}

// Round 8
// 1826.037 us; speedup vs baseline: 1.3702x; 1.1243x over previous
//
#include <hip/hip_runtime.h>

typedef float v2f __attribute__((ext_vector_type(2)));

#define QN 8192   // trajectories
#define MN 2048   // time steps
#define HN 64     // hidden units
#define LPT 16    // lanes per trajectory (4 trajectories per wave)
#define UPL 4     // hidden units per lane

// DPP butterfly add. old = v (not 0) so no zero-materialization mov is needed;
// with full row/bank masks every lane is written, so semantics are identical.
template <int CTRL>
__device__ __forceinline__ float dpp_add(float v) {
    int m = __builtin_amdgcn_update_dpp(__float_as_int(v), __float_as_int(v),
                                        CTRL, 0xf, 0xf, true);
    return v + __int_as_float(m);
}
#define DPP_QUAD_XOR1 0xB1   // quad_perm [1,0,3,2]
#define DPP_QUAD_XOR2 0x4E   // quad_perm [2,3,0,1]
#define DPP_HALF_MIRR 0x141  // row_half_mirror
#define DPP_ROW_MIRR  0x140  // row_mirror

__device__ __forceinline__ v2f vfma(v2f a, v2f b, v2f c) {
    return __builtin_elementwise_fma(a, b, c);
}

__global__ __launch_bounds__(256, 2) void rk4_nss_kernel(
    const float* __restrict__ x0p,   // (Q,2)
    const float* __restrict__ up,    // (M,Q)
    const float* __restrict__ W1,    // (3,H)
    const float* __restrict__ b1,    // (H)
    const float* __restrict__ W2,    // (H,2)
    const float* __restrict__ b2,    // (2)
    float* __restrict__ out)         // (M,Q,2)
{
    const int tid  = blockIdx.x * 256 + threadIdx.x;
    const int lane = threadIdx.x & (LPT - 1);
    const int traj = tid >> 4;

    const float SC = 2.8853900817779268f;  // 2*log2(e): e^{2x} = 2^(SC*x)
    const float CL = 27.0f;  // clamp (scaled): tanh(27/SC)==1.0f in f32;
                             // pair den-product <= ~2^54, cannot overflow.

    // Lane owns hidden units j = lane + k*16, pairs (0,1) and (2,3) packed as
    // v2f so the preactivation runs on v_pk_fma_f32. W1,b1 pre-scaled by SC.
    // tanh = 1 - 2/(e^{2x}+1): "+1" parts folded into c0,c1 (applied once per
    // step, outside the fevals), accumulate inv*(-2*W2).
    v2f W10[2], W11[2], W12[2], BS[2];
    float w20n[UPL], w21n[UPL];
#pragma unroll
    for (int k = 0; k < UPL; ++k) {
        const int j = lane + k * LPT;
        W10[k >> 1][k & 1] = W1[j] * SC;
        W11[k >> 1][k & 1] = W1[HN + j] * SC;
        W12[k >> 1][k & 1] = W1[2 * HN + j] * SC;
        BS[k >> 1][k & 1]  = b1[j] * SC;
        w20n[k] = -2.0f * W2[2 * j];
        w21n[k] = -2.0f * W2[2 * j + 1];
    }
    float c0 = b2[0], c1 = b2[1];
    for (int j = 0; j < HN; ++j) {   // init-time only; W2 is 512 B, cache-hot
        c0 += W2[2 * j];
        c1 += W2[2 * j + 1];
    }
    const float c0h = 0.5f * c0, c1h = 0.5f * c1;

    float xa = x0p[2 * traj];
    float xb = x0p[2 * traj + 1];

    float2* op = reinterpret_cast<float2*>(out) + traj;
    const bool writer = (lane == 0);

    v2f PB[2];  // u-dependent preactivation part, constant across the 4 fevals

    // Returns RAW p0,p1 (without +c): k_true = p + c, folded by the caller.
    auto feval = [&](float ia, float ib, float& p0o, float& p1o) {
        v2f IA = {ia, ia};
        v2f IB = {ib, ib};
        v2f PRE0 = vfma(W10[0], IA, vfma(W11[0], IB, PB[0]));
        v2f PRE1 = vfma(W10[1], IA, vfma(W11[1], IB, PB[1]));
        float den0 = __builtin_amdgcn_exp2f(__builtin_amdgcn_fmed3f(PRE0.x, -CL, CL)) + 1.0f;
        float den1 = __builtin_amdgcn_exp2f(__builtin_amdgcn_fmed3f(PRE0.y, -CL, CL)) + 1.0f;
        float den2 = __builtin_amdgcn_exp2f(__builtin_amdgcn_fmed3f(PRE1.x, -CL, CL)) + 1.0f;
        float den3 = __builtin_amdgcn_exp2f(__builtin_amdgcn_fmed3f(PRE1.y, -CL, CL)) + 1.0f;
        // Pair-batched reciprocal (R3-proven): 2 independent rcp chains.
        float d01 = den0 * den1;
        float d23 = den2 * den3;
        float r01 = __builtin_amdgcn_rcpf(d01);
        float r23 = __builtin_amdgcn_rcpf(d23);
        float inv0 = r01 * den1;
        float inv1 = r01 * den0;
        float inv2 = r23 * den3;
        float inv3 = r23 * den2;

        float p0 = fmaf(inv0, w20n[0],
                   fmaf(inv1, w20n[1],
                   fmaf(inv2, w20n[2], inv3 * w20n[3])));
        float p1 = fmaf(inv0, w21n[0],
                   fmaf(inv1, w21n[1],
                   fmaf(inv2, w21n[2], inv3 * w21n[3])));

        p0 = dpp_add<DPP_QUAD_XOR1>(p0);  p1 = dpp_add<DPP_QUAD_XOR1>(p1);
        p0 = dpp_add<DPP_QUAD_XOR2>(p0);  p1 = dpp_add<DPP_QUAD_XOR2>(p1);
        p0 = dpp_add<DPP_HALF_MIRR>(p0);  p1 = dpp_add<DPP_HALF_MIRR>(p1);
        p0 = dpp_add<DPP_ROW_MIRR>(p0);   p1 = dpp_add<DPP_ROW_MIRR>(p1);
        p0o = p0;
        p1o = p1;
    };

    // One RK4 step with the +c folds:
    //   k_i = p_i + c ;  x+0.5*k1 = (x+0.5c) + 0.5*p1 ;  x+k3 = (x+c) + p3
    //   x_new = x + (k1+2k2+2k3+k4)/6 = (x+c) + (p1+2p2+2p3+p4)/6
    auto step = [&](float u, int /*unused*/) {
        v2f UU = {u, u};
        PB[0] = vfma(W12[0], UU, BS[0]);
        PB[1] = vfma(W12[1], UU, BS[1]);

        const float xha = xa + c0h, xhb = xb + c1h;   // x + 0.5c
        const float xca = xa + c0,  xcb = xb + c1;    // x + c

        float p1a, p1b, p2a, p2b, p3a, p3b, p4a, p4b;
        feval(xa, xb, p1a, p1b);
        feval(fmaf(0.5f, p1a, xha), fmaf(0.5f, p1b, xhb), p2a, p2b);
        feval(fmaf(0.5f, p2a, xha), fmaf(0.5f, p2b, xhb), p3a, p3b);
        feval(xca + p3a, xcb + p3b, p4a, p4b);

        float ta = p2a + p3a, sa = p1a + p4a;
        xa = fmaf(1.0f / 6.0f, fmaf(2.0f, ta, sa), xca);
        float tb = p2b + p3b, sb = p1b + p4b;
        xb = fmaf(1.0f / 6.0f, fmaf(2.0f, tb, sb), xcb);
    };

    float u0 = up[traj];
    float u1 = up[QN + traj];

    for (int t = 0; t < MN; t += 2) {
        // Prefetch 2 steps ahead (consumed next unrolled iteration).
        const float u2 = (t + 2 < MN) ? up[(t + 2) * QN + traj] : 0.0f;
        const float u3 = (t + 3 < MN) ? up[(t + 3) * QN + traj] : 0.0f;

        // Output is the state BEFORE the update.
        if (writer) *op = make_float2(xa, xb);
        op += QN;
        step(u0, t);

        if (writer) *op = make_float2(xa, xb);
        op += QN;
        step(u1, t + 1);

        u0 = u2;
        u1 = u3;
    }
}

extern "C" void kernel_launch(void* const* d_in, const int* in_sizes, int n_in,
                              void* d_out, int out_size, void* d_ws, size_t ws_size,
                              hipStream_t stream) {
    const float* x0 = (const float*)d_in[0];
    const float* u  = (const float*)d_in[1];
    const float* W1 = (const float*)d_in[2];
    const float* b1 = (const float*)d_in[3];
    const float* W2 = (const float*)d_in[4];
    const float* b2 = (const float*)d_in[5];
    float* out = (float*)d_out;

    // 8192 trajectories * 16 lanes = 131072 threads = 512 blocks of 256
    // = 2048 waves = exactly 2 waves/SIMD.
    const int threads = 256;
    const int blocks  = (QN * LPT) / threads;
    rk4_nss_kernel<<<blocks, threads, 0, stream>>>(x0, u, W1, b1, W2, b2, out);
}